// Round 6
// baseline (403995.361 us; speedup 1.0000x reference)
//
#include <hip/hip_runtime.h>
#include <cstdint>

#define TPB 256
#define GRID_WGS 256

// problem dims
#define NB    32
#define TIN   400
#define TOUT  500
#define NMEL  80
#define EDIM  512
#define ARNN  1024
#define PDIM  256
#define ADIM  128
#define NGATE 4096

#define KSA 7        // attention-LSTM K = 1792 = 7 x 256
#define KSD 10       // decoder-LSTM   K = 2560 = 10 x 256
#define NTASK_A 112  // 16 j-tiles x 7 k-chunks
#define NTASK   272  // + 16 j-tiles x 10 k-chunks

// double-region offsets (units: doubles)
#define PM_OFF   0          // pmT[b][a][t] [32][128][400]
#define WFC_OFF  1638400    // [128][62]
#define AH_OFF   1646336
#define AC_OFF   1679104
#define DH_OFF   1711872
#define DC_OFF   1744640
#define CTX_OFF  1777408
#define AW_OFF   1793792
#define AWC_OFF  1806592
#define EN_OFF   1819392
#define PQ_OFF   1832192
#define PRE0_OFF 1836288
#define PRE1_OFF 1844480
#define DBL_END  1852672
// float region (units: floats, base = (float*)(ws + DBL_END))
#define PAF_OFF  0          // A partials [7][32][4096]
#define PDF_OFF  917504     // D partials [10][32][4096]
#define F_END    2228224
// barrier region: 16 uints after float region
#define WS_BYTES ((size_t)DBL_END*8 + (size_t)F_END*4 + 64)

#define MEL_OFF  0
#define GATE_OFF 1280000
#define AL_OFF   1296000

// ---------------- device-scope grid barrier (no cooperative launch) ----------------
__device__ __forceinline__ void gridbar(unsigned* cnt, unsigned* gen, int tid){
  __syncthreads();
  if (tid == 0){
    __threadfence();   // release prior global writes
    unsigned g = __hip_atomic_load(gen, __ATOMIC_RELAXED, __HIP_MEMORY_SCOPE_AGENT);
    unsigned arrived = __hip_atomic_fetch_add(cnt, 1u, __ATOMIC_ACQ_REL, __HIP_MEMORY_SCOPE_AGENT);
    if (arrived == GRID_WGS - 1){
      __hip_atomic_store(cnt, 0u, __ATOMIC_RELAXED, __HIP_MEMORY_SCOPE_AGENT);
      __hip_atomic_fetch_add(gen, 1u, __ATOMIC_RELEASE, __HIP_MEMORY_SCOPE_AGENT);
    } else {
      while (__hip_atomic_load(gen, __ATOMIC_ACQUIRE, __HIP_MEMORY_SCOPE_AGENT) == g){
        __builtin_amdgcn_s_sleep(2);
      }
    }
    __threadfence();   // acquire side
  }
  __syncthreads();
}

// ---------------- threefry2x32 core (bit-exact JAX) ----------------
__device__ __forceinline__ uint32_t rotl32(uint32_t v, int r){ return (v<<r)|(v>>(32-r)); }

__device__ __forceinline__ void tf_block(uint32_t k0, uint32_t k1, uint32_t x0, uint32_t x1,
                                         uint32_t& y0, uint32_t& y1){
  uint32_t k2 = k0 ^ k1 ^ 0x1BD11BDAu;
  x0 += k0; x1 += k1;
#define TF4(r0,r1,r2,r3,ka,kb,inc) \
  x0 += x1; x1 = rotl32(x1,r0); x1 ^= x0; \
  x0 += x1; x1 = rotl32(x1,r1); x1 ^= x0; \
  x0 += x1; x1 = rotl32(x1,r2); x1 ^= x0; \
  x0 += x1; x1 = rotl32(x1,r3); x1 ^= x0; \
  x0 += (ka); x1 += (kb) + (inc);
  TF4(13,15,26,6,  k1,k2,1u)
  TF4(17,29,16,24, k2,k0,2u)
  TF4(13,15,26,6,  k0,k1,3u)
  TF4(17,29,16,24, k1,k2,4u)
  TF4(13,15,26,6,  k2,k0,5u)
#undef TF4
  y0 = x0; y1 = x1;
}

// ---- PARTITIONABLE threefry (jax_threefry_partitionable=True, modern JAX default) ----
// random_bits(key, 32, shape)[i]: counter = (hi(i)=0, lo(i)=i); bits = y0 ^ y1.
// uniform(bits) < 0.5  <=>  top bit of bits == 0.
__device__ __forceinline__ bool tf_keep_part(uint32_t k0, uint32_t k1, uint32_t i){
  uint32_t y0, y1;
  tf_block(k0, k1, 0u, i, y0, y1);
  return (((y0 ^ y1) >> 31) == 0u);
}

// ---------------- precompute kernels (fp64) ----------------
__global__ __launch_bounds__(TPB) void pm_kernel(
    const float* __restrict__ memory, const float* __restrict__ Wm, double* __restrict__ pmT)
{
  const int bt = blockIdx.x;           // b*400 + t
  const int b = bt / TIN, t2 = bt - b*TIN;
  const int tid = threadIdx.x;
  __shared__ double sm[EDIM];
  __shared__ double sp[TPB];
  for (int i = tid; i < EDIM; i += TPB) sm[i] = (double)memory[(size_t)bt*EDIM + i];
  __syncthreads();
  const int a = tid & 127, hf = tid >> 7;
  const float* w = Wm + (size_t)a*EDIM + hf*256;
  const double* x = sm + hf*256;
  double s = 0.0;
  for (int e = 0; e < 256; ++e) s += (double)w[e]*x[e];
  sp[tid] = s;
  __syncthreads();
  if (tid < ADIM) pmT[((size_t)b*ADIM + tid)*TIN + t2] = sp[tid] + sp[tid+128];
}

__global__ __launch_bounds__(TPB) void wfc_kernel(
    const float* __restrict__ Wd, const float* __restrict__ Wc, double* __restrict__ wfc)
{
  for (int o = threadIdx.x; o < ADIM*62; o += TPB){
    int a = o / 62, ck = o - a*62;
    double s = 0.0;
    for (int f = 0; f < 32; ++f) s += (double)Wd[a*32+f]*(double)Wc[f*62 + ck];
    wfc[o] = s;
  }
}

__global__ void bar_init_kernel(unsigned* bar){ bar[threadIdx.x] = 0u; }
__global__ void sentinel_kernel(float* out, float val){ out[0] = val; }

// ---------------- main persistent kernel ----------------
struct DecParams {
  const float *memory, *dec;
  const float *Wpre1, *Wpre2;
  const float *WihA,*WhhA,*bihA,*bhhA;
  const float *Wq,*v;
  const float *WihD,*WhhD,*bihD,*bhhD;
  const float *Wp,*bp,*Wg,*bg;
  const unsigned char* mask;
  double* ws;
  float* out;
};

__device__ __forceinline__ double sigd(double x){ return 1.0/(1.0+exp(-x)); }

__global__ __launch_bounds__(TPB, 1) void decoder_main(DecParams P)
{
  const int wg = blockIdx.x, tid = threadIdx.x;
  const int nwg = GRID_WGS;
  __shared__ __align__(16) double sb[4096];   // 32 KB

  double* ws  = P.ws;
  double* pmT = ws + PM_OFF;   double* wfc = ws + WFC_OFF;
  double* ah  = ws + AH_OFF;   double* ac  = ws + AC_OFF;
  double* dh  = ws + DH_OFF;   double* dc  = ws + DC_OFF;
  double* ctx = ws + CTX_OFF;  double* aw  = ws + AW_OFF;  double* awc = ws + AWC_OFF;
  double* en  = ws + EN_OFF;   double* pq  = ws + PQ_OFF;
  float*  pAf = (float*)(ws + DBL_END);
  float*  pDf = pAf + PDF_OFF;
  unsigned* bar = (unsigned*)(pAf + F_END);   // bar[0]=count, bar[1]=gen (init'd by bar_init_kernel)

  // zero recurrent state + pre buffers (AH..DBL_END contiguous doubles)
  for (int i = wg*TPB + tid; i < DBL_END - AH_OFF; i += nwg*TPB) ah[i] = 0.0;
  gridbar(bar, bar+1, tid);

  #pragma unroll 1
  for (int t = 0; t <= TOUT; ++t){
    const double* pre_cur = ws + ((t & 1) ? PRE1_OFF : PRE0_OFF);

    // ---- PH1: fp64 gate-GEMM partials (A for step t, D for step t-1) ----
    for (int task = wg; task < NTASK; task += nwg){
      const bool isA = task < NTASK_A;
      if (isA ? (t < TOUT) : (t > 0)){
        int jt, ks;
        if (isA){ jt = task / KSA; ks = task - jt*KSA; }
        else    { int r = task - NTASK_A; jt = r / KSD; ks = r - jt*KSD; }
        const int kbase = ks*256;
        const int jg = tid & 63, bg = tid >> 6;
        const int j0 = jt*256 + jg*4;
        const float* wbase; int rowlen, koff;
        if (isA){
          if (kbase < 768){ wbase = P.WihA; rowlen = 768;  koff = kbase; }
          else            { wbase = P.WhhA; rowlen = 1024; koff = kbase-768; }
        } else {
          if (kbase < 1536){ wbase = P.WihD; rowlen = 1536; koff = kbase; }
          else             { wbase = P.WhhD; rowlen = 1024; koff = kbase-1536; }
        }
        const float* wr0 = wbase + (size_t)(j0+0)*rowlen + koff;
        const float* wr1 = wbase + (size_t)(j0+1)*rowlen + koff;
        const float* wr2 = wbase + (size_t)(j0+2)*rowlen + koff;
        const float* wr3 = wbase + (size_t)(j0+3)*rowlen + koff;
        double acc[32];
        #pragma unroll
        for (int i = 0; i < 32; ++i) acc[i] = 0.0;

        #pragma unroll 1
        for (int half = 0; half < 2; ++half){
          const int kb2 = kbase + half*128;
          if (isA){
            for (int i = tid; i < NB*128; i += TPB){
              const int b = i >> 7, kg = kb2 + (i & 127);
              double xv;
              if (kg < 256)       xv = pre_cur[(b<<8) + kg];
              else if (kg < 768)  xv = ctx[b*EDIM + (kg-256)];
              else                xv = ah[b*ARNN + (kg-768)];
              sb[i] = xv;
            }
          } else {
            for (int i = tid; i < NB*128; i += TPB){
              const int b = i >> 7, kg = kb2 + (i & 127);
              double xv;
              if (kg < 1024)      xv = ah[b*ARNN + kg];
              else if (kg < 1536) xv = ctx[b*EDIM + (kg-1024)];
              else                xv = dh[b*ARNN + (kg-1536)];
              sb[i] = xv;
            }
          }
          __syncthreads();
          const int kadd = half*128;
          #pragma unroll 1
          for (int kk = 0; kk < 128; kk += 4){
            const float4 f0 = *(const float4*)(wr0 + kadd + kk);
            const float4 f1 = *(const float4*)(wr1 + kadd + kk);
            const float4 f2 = *(const float4*)(wr2 + kadd + kk);
            const float4 f3 = *(const float4*)(wr3 + kadd + kk);
            const double w00=f0.x,w01=f0.y,w02=f0.z,w03=f0.w;
            const double w10=f1.x,w11=f1.y,w12=f1.z,w13=f1.w;
            const double w20=f2.x,w21=f2.y,w22=f2.z,w23=f2.w;
            const double w30=f3.x,w31=f3.y,w32=f3.z,w33=f3.w;
            #pragma unroll
            for (int bi = 0; bi < 8; ++bi){
              const double* xp = sb + (((bg<<3)+bi)<<7) + kk;
              const double x0=xp[0], x1=xp[1], x2=xp[2], x3=xp[3];
              acc[bi*4+0] += w00*x0 + w01*x1 + w02*x2 + w03*x3;
              acc[bi*4+1] += w10*x0 + w11*x1 + w12*x2 + w13*x3;
              acc[bi*4+2] += w20*x0 + w21*x1 + w22*x2 + w23*x3;
              acc[bi*4+3] += w30*x0 + w31*x1 + w32*x2 + w33*x3;
            }
          }
          __syncthreads();
        }

        float* pbase = (isA ? pAf : pDf) + ((size_t)ks*NB)*NGATE;
        #pragma unroll
        for (int bi = 0; bi < 8; ++bi){
          const int b = (bg<<3) + bi;
          float4 v4 = { (float)acc[bi*4+0], (float)acc[bi*4+1],
                        (float)acc[bi*4+2], (float)acc[bi*4+3] };
          *(float4*)(pbase + (size_t)b*NGATE + j0) = v4;
        }
      }
    }
    gridbar(bar, bar+1, tid);

    // ---- PH1b: LSTM reduce + activations (+ pq = Wq @ ah), fp64 ----
    if (wg < NB){
      if (t < TOUT){
        const int b = wg;
        for (int h = tid; h < ARNN; h += TPB){
          double g0 = (double)P.bihA[h]      + (double)P.bhhA[h];
          double g1 = (double)P.bihA[1024+h] + (double)P.bhhA[1024+h];
          double g2 = (double)P.bihA[2048+h] + (double)P.bhhA[2048+h];
          double g3 = (double)P.bihA[3072+h] + (double)P.bhhA[3072+h];
          for (int p2 = 0; p2 < KSA; ++p2){
            const float* pp = pAf + ((size_t)p2*NB + b)*NGATE;
            g0 += (double)pp[h]; g1 += (double)pp[1024+h];
            g2 += (double)pp[2048+h]; g3 += (double)pp[3072+h];
          }
          const double cp = ac[b*ARNN + h];
          const double cn = sigd(g1)*cp + sigd(g0)*tanh(g2);
          const double hn = sigd(g3)*tanh(cn);
          ac[b*ARNN+h] = cn; ah[b*ARNN+h] = hn; sb[h] = hn;
        }
        __syncthreads();
        {
          const int a2 = tid >> 1, hf = tid & 1;
          const float* wq = P.Wq + (size_t)a2*ARNN + hf*512;
          const double* xh = sb + hf*512;
          double s = 0.0;
          for (int h2 = 0; h2 < 512; ++h2) s += (double)wq[h2]*xh[h2];
          sb[1024 + tid] = s;
        }
        __syncthreads();
        if (tid < ADIM) pq[b*ADIM + tid] = sb[1024 + 2*tid] + sb[1024 + 2*tid + 1];
      }
    } else if (wg < 2*NB){
      if (t > 0){
        const int b = wg - NB;
        for (int h = tid; h < ARNN; h += TPB){
          double g0 = (double)P.bihD[h]      + (double)P.bhhD[h];
          double g1 = (double)P.bihD[1024+h] + (double)P.bhhD[1024+h];
          double g2 = (double)P.bihD[2048+h] + (double)P.bhhD[2048+h];
          double g3 = (double)P.bihD[3072+h] + (double)P.bhhD[3072+h];
          for (int p2 = 0; p2 < KSD; ++p2){
            const float* pp = pDf + ((size_t)p2*NB + b)*NGATE;
            g0 += (double)pp[h]; g1 += (double)pp[1024+h];
            g2 += (double)pp[2048+h]; g3 += (double)pp[3072+h];
          }
          const double cp = dc[b*ARNN + h];
          const double cn = sigd(g1)*cp + sigd(g0)*tanh(g2);
          const double hn = sigd(g3)*tanh(cn);
          dc[b*ARNN+h] = cn; dh[b*ARNN+h] = hn;
        }
      }
    }
    gridbar(bar, bar+1, tid);

    // ---- PH2: attention energies (t) + mel/gate (t-1), fp64 ----
    if (wg < 224){
      if (t < TOUT){
        const int b = wg / 7, tt = wg - b*7;
        const int tbase = tt*64;
        if (tid < ADIM) sb[tid] = pq[b*ADIM + tid];
        for (int i = tid; i < 94; i += TPB){
          int tg = tbase - 15 + i;
          sb[128 + i] = (tg >= 0 && tg < TIN) ? aw[b*TIN + tg] : 0.0;
        }
        for (int i = tid; i < 94; i += TPB){
          int tg = tbase - 15 + i;
          sb[222 + i] = (tg >= 0 && tg < TIN) ? awc[b*TIN + tg] : 0.0;
        }
        __syncthreads();
        const int wv = tid >> 6, lane = tid & 63;
        const int tg = tbase + lane;
        double esum = 0.0;
        if (tg < TIN){
          double w0r[31], w1r[31];
          #pragma unroll
          for (int k = 0; k < 31; ++k){ w0r[k] = sb[128 + lane + k]; w1r[k] = sb[222 + lane + k]; }
          const double* pmrow = pmT + (size_t)b*ADIM*TIN + tg;
          for (int a2 = wv*32; a2 < wv*32 + 32; ++a2){
            const double* wf = wfc + a2*62;
            double cv = 0.0;
            #pragma unroll
            for (int k = 0; k < 31; ++k) cv += wf[k]*w0r[k];
            #pragma unroll
            for (int k = 0; k < 31; ++k) cv += wf[31+k]*w1r[k];
            const double e = sb[a2] + cv + pmrow[(size_t)a2*TIN];
            esum += (double)P.v[a2]*tanh(e);
          }
        }
        sb[640 + wv*64 + lane] = esum;
        __syncthreads();
        if (tid < 64){
          const int tg2 = tbase + tid;
          if (tg2 < TIN){
            double e = sb[640+tid] + sb[704+tid] + sb[768+tid] + sb[832+tid];
            if (P.mask[b*TIN + tg2]) e = -1e9;
            en[b*TIN + tg2] = e;
          }
        }
      }
    } else if (wg < 256){
      if (t > 0){
        const int b = wg - 224, ts = t-1;
        for (int i = tid; i < 1536; i += TPB)
          sb[i] = (i < 1024) ? dh[b*ARNN + i] : ctx[b*EDIM + (i-1024)];
        __syncthreads();
        const int o = tid >> 1, hf = tid & 1;
        double s = 0.0;
        if (o <= 80){
          const float* wr = ((o < 80) ? (P.Wp + (size_t)o*1536) : P.Wg) + hf*768;
          const double* xr = sb + hf*768;
          for (int m2 = 0; m2 < 768; ++m2) s += (double)wr[m2]*xr[m2];
        }
        sb[1600 + tid] = s;
        __syncthreads();
        if (tid <= 80){
          double val = sb[1600 + 2*tid] + sb[1600 + 2*tid + 1];
          if (tid < 80) P.out[MEL_OFF + ((size_t)b*NMEL + tid)*TOUT + ts] = (float)(val + (double)P.bp[tid]);
          else          P.out[GATE_OFF + (size_t)b*TOUT + ts] = (float)(val + (double)P.bg[0]);
        }
      }
    }
    gridbar(bar, bar+1, tid);

    // ---- PH3: softmax + context (WGs 0..31) | prenet t+1 (WGs 32..63), fp64 ----
    if (wg < NB){
      if (t < TOUT){
        const int b = wg;
        double m = -1.0e300;
        for (int i = tid; i < TIN; i += TPB) m = fmax(m, en[b*TIN + i]);
        sb[tid] = m; __syncthreads();
        for (int s2 = TPB/2; s2 > 0; s2 >>= 1){
          if (tid < s2) sb[tid] = fmax(sb[tid], sb[tid+s2]);
          __syncthreads();
        }
        const double mx = sb[0];
        __syncthreads();
        double ssum = 0.0;
        for (int i = tid; i < TIN; i += TPB){
          double u = exp(en[b*TIN+i] - mx);
          sb[512 + i] = u; ssum += u;
        }
        sb[tid] = ssum; __syncthreads();
        for (int s2 = TPB/2; s2 > 0; s2 >>= 1){
          if (tid < s2) sb[tid] += sb[tid+s2];
          __syncthreads();
        }
        const double tot = sb[0];
        __syncthreads();
        for (int i = tid; i < TIN; i += TPB){
          double a2 = sb[512+i] / tot;
          sb[512+i] = a2;
          aw[b*TIN+i] = a2;
          awc[b*TIN+i] += a2;
          P.out[AL_OFF + ((size_t)b*TOUT + t)*TIN + i] = (float)a2;
        }
        __syncthreads();
        for (int e2 = tid; e2 < EDIM; e2 += TPB){
          const float* mrow = P.memory + (size_t)b*TIN*EDIM + e2;
          double s = 0.0;
          for (int t2 = 0; t2 < TIN; ++t2) s += sb[512+t2]*(double)mrow[(size_t)t2*EDIM];
          ctx[b*EDIM + e2] = s;
        }
      }
    } else if (wg < 2*NB){
      if (t < TOUT-1){
        const int b = wg - NB, t1 = t + 1;
        double* pre_next = ws + ((t1 & 1) ? PRE1_OFF : PRE0_OFF);
        for (int m = tid; m < NMEL; m += TPB)
          sb[m] = (double)P.dec[((size_t)b*NMEL + m)*TOUT + (t1-1)];
        __syncthreads();
        // PARTITIONABLE split of key(42)=(0,42): dk_i = full output of block(0, i)
        uint32_t d1k0, d1k1, d2k0, d2k1;
        tf_block(0u, 42u, 0u, 0u, d1k0, d1k1);   // dk1 = (y0, y1) @ counter 0
        tf_block(0u, 42u, 0u, 1u, d2k0, d2k1);   // dk2 = (y0, y1) @ counter 1
        const uint32_t flat = ((uint32_t)(t1*NB + b))*PDIM + tid;
        {
          const float* w = P.Wpre1 + tid*NMEL;
          double s = 0.0;
          for (int m = 0; m < NMEL; ++m) s += sb[m]*(double)w[m];
          double hv = tf_keep_part(d1k0, d1k1, flat) ? s*2.0 : 0.0;
          sb[128 + tid] = fmax(hv, 0.0);
        }
        __syncthreads();
        {
          const float* w = P.Wpre2 + tid*PDIM;
          double s = 0.0;
          for (int m = 0; m < PDIM; ++m) s += sb[128+m]*(double)w[m];
          double pv = tf_keep_part(d2k0, d2k1, flat) ? s*2.0 : 0.0;
          pre_next[(b<<8) + tid] = fmax(pv, 0.0);
        }
      }
    }
    gridbar(bar, bar+1, tid);
  }
}

extern "C" void kernel_launch(void* const* d_in, const int* in_sizes, int n_in,
                              void* d_out, int out_size, void* d_ws, size_t ws_size,
                              hipStream_t stream)
{
  const float* memory = (const float*)d_in[0];
  const float* dec    = (const float*)d_in[1];
  const unsigned char* mask = (const unsigned char*)d_in[2];
  const float* W_pre1 = (const float*)d_in[3];
  const float* W_pre2 = (const float*)d_in[4];
  const float* WihA   = (const float*)d_in[5];
  const float* WhhA   = (const float*)d_in[6];
  const float* bihA   = (const float*)d_in[7];
  const float* bhhA   = (const float*)d_in[8];
  const float* Wq     = (const float*)d_in[9];
  const float* Wm     = (const float*)d_in[10];
  const float* v      = (const float*)d_in[11];
  const float* Wc     = (const float*)d_in[12];
  const float* Wd     = (const float*)d_in[13];
  const float* WihD   = (const float*)d_in[14];
  const float* WhhD   = (const float*)d_in[15];
  const float* bihD   = (const float*)d_in[16];
  const float* bhhD   = (const float*)d_in[17];
  const float* Wp     = (const float*)d_in[18];
  const float* bp     = (const float*)d_in[19];
  const float* Wg     = (const float*)d_in[20];
  const float* bg     = (const float*)d_in[21];

  double* ws = (double*)d_ws;
  float* out = (float*)d_out;

  if (ws_size < WS_BYTES){
    sentinel_kernel<<<1, 1, 0, stream>>>(out, 12345.0f);   // diagnostic: ws too small
    return;
  }

  unsigned* bar = (unsigned*)((float*)(ws + DBL_END) + F_END);
  bar_init_kernel<<<1, 16, 0, stream>>>(bar);
  pm_kernel<<<NB*TIN, TPB, 0, stream>>>(memory, Wm, ws + PM_OFF);
  wfc_kernel<<<1, TPB, 0, stream>>>(Wd, Wc, ws + WFC_OFF);

  DecParams P;
  P.memory = memory; P.dec = dec;
  P.Wpre1 = W_pre1; P.Wpre2 = W_pre2;
  P.WihA = WihA; P.WhhA = WhhA; P.bihA = bihA; P.bhhA = bhhA;
  P.Wq = Wq; P.v = v;
  P.WihD = WihD; P.WhhD = WhhD; P.bihD = bihD; P.bhhD = bhhD;
  P.Wp = Wp; P.bp = bp; P.Wg = Wg; P.bg = bg;
  P.mask = mask; P.ws = ws; P.out = out;

  decoder_main<<<GRID_WGS, TPB, 0, stream>>>(P);
}